// Round 7
// baseline (29.399 us; speedup 1.0000x reference)
//
#include <hip/hip_runtime.h>
#include <math.h>

// GBST forward. B=8, L=2048, D=256, NGRAM=4. R18 = R17 + latency/VALU cuts:
//  1. FULL-DEPTH weight prefetch: all 8 proj slabs (64 VGPR) issued BEFORE
//     conv (~2k cy cover -> zero exposed latency in proj GEMM); 6 FF slabs
//     at B1 (covered by wts+mix), last 2 after mix. GEMMs are pure
//     MFMA+ds_read runs, no interleaved loads (R17: 4-deep ping-pong left
//     ~500cy exposed per late phase).
//  2. v_cvt_pk_bf16_f32 for conv/mix LDS writes (1 op per 2 values vs ~7
//     for manual RNE pair) and x2 kept in f32 (no epilogue pack, no mix
//     unpack): ~240 VALU/thread cut (~30%). LDS 53.8 -> 78.3 KB, still
//     2 blocks/CU. x2-f32 also slightly improves numerics.
// Rationale: R14 counters showed all pipes <15% busy at ~100k cy/dispatch
// -> low effective clock + latency chains dominate; cut cycles and ns.
// Kept: NT out stores, hoisted tokens, vectorized k_prep, M=48/8-wave/3-bar.

#define D_ 256
#define M_ 48                 // positions per block (3 stripes of 16; 12 | 48)
#define BPB 43                // ceil(2048/48)
#define LSTR 264              // x_lds ushort stride: 528B, 16B-aligned
#define X2S 260               // x2f float stride: 1040B

typedef __attribute__((ext_vector_type(8))) short bf16x8;
typedef __attribute__((ext_vector_type(4))) float f32x4;

__device__ __forceinline__ ushort f2bf(float f) {
    union { float f; unsigned u; } v; v.f = f;
    unsigned r = v.u + 0x7fffu + ((v.u >> 16) & 1u);   // RNE
    return (ushort)(r >> 16);
}
__device__ __forceinline__ float bf2f(ushort h) {
    union { unsigned u; float f; } v; v.u = ((unsigned)h) << 16;
    return v.f;
}
// packed RNE f32x2 -> bf16x2 (lo = first arg)
__device__ __forceinline__ unsigned cvtpk(float lo, float hi) {
    unsigned r;
    asm("v_cvt_pk_bf16_f32 %0, %1, %2" : "=v"(r) : "v"(lo), "v"(hi));
    return r;
}

// load one k8-slab (2 B-frags for this wave's n-pair), fragment-major
#define LDB2(v0, v1, W, K8) do { \
    const ushort* bp_ = (W) + ((size_t)((K8) * 16 + w * 2) * 64 + ln) * 8; \
    v0 = *(const bf16x8*)(bp_); \
    v1 = *(const bf16x8*)(bp_ + 512); \
} while (0)

// 6 MFMAs for one k8: 2 n-tiles x 3 m-stripes
#define MFMA6(ACC, K8, v0, v1) do { \
    bf16x8 a0_ = *(const bf16x8*)&x_lds[lr][(K8) * 32 + koff]; \
    bf16x8 a1_ = *(const bf16x8*)&x_lds[16 + lr][(K8) * 32 + koff]; \
    bf16x8 a2_ = *(const bf16x8*)&x_lds[32 + lr][(K8) * 32 + koff]; \
    ACC[0][0] = __builtin_amdgcn_mfma_f32_16x16x32_bf16(a0_, v0, ACC[0][0], 0, 0, 0); \
    ACC[1][0] = __builtin_amdgcn_mfma_f32_16x16x32_bf16(a1_, v0, ACC[1][0], 0, 0, 0); \
    ACC[2][0] = __builtin_amdgcn_mfma_f32_16x16x32_bf16(a2_, v0, ACC[2][0], 0, 0, 0); \
    ACC[0][1] = __builtin_amdgcn_mfma_f32_16x16x32_bf16(a0_, v1, ACC[0][1], 0, 0, 0); \
    ACC[1][1] = __builtin_amdgcn_mfma_f32_16x16x32_bf16(a1_, v1, ACC[1][1], 0, 0, 0); \
    ACC[2][1] = __builtin_amdgcn_mfma_f32_16x16x32_bf16(a2_, v1, ACC[2][1], 0, 0, 0); \
} while (0)

#define SBAR __builtin_amdgcn_sched_barrier(0)

// ---------------------------------------------------------------------------
// K0: proj_w/ff_w -> bf16 FRAGMENT-MAJOR, 2 elements/thread (j,j+1 pairs):
// wq[((k8*16+nb)*64+ln)*8+j] = w[(nb*16+(ln&15))*256 + k8*32+(ln>>4)*8+j]
// ---------------------------------------------------------------------------
__global__ __launch_bounds__(256) void k_prep(
    const float* __restrict__ pw, const float* __restrict__ fw,
    ushort* __restrict__ wqp, ushort* __restrict__ wqf)
{
    int i = (blockIdx.x * 256 + threadIdx.x) * 2;   // 0,2,..,65534
    int j  = i & 7;                                  // even
    int ln = (i >> 3) & 63;
    int nb = (i >> 9) & 15;
    int k8 = i >> 13;
    int er = nb * 16 + (ln & 15);
    int k  = k8 * 32 + (ln >> 4) * 8 + j;
    float2 p2 = *(const float2*)(pw + er * D_ + k);
    float2 f2 = *(const float2*)(fw + er * D_ + k);
    *(unsigned*)(wqp + i) = cvtpk(p2.x, p2.y);
    *(unsigned*)(wqf + i) = cvtpk(f2.x, f2.y);
}

// ---------------------------------------------------------------------------
// K1: 512 threads / 8 waves, M=48 positions, 3 barriers, full-depth prefetch.
// ---------------------------------------------------------------------------
__global__ __launch_bounds__(512, 4) void k_main(
    const int* __restrict__ seq, const float* __restrict__ emb,
    const float* __restrict__ conv_w, const float* __restrict__ conv_b,
    const ushort* __restrict__ wqp, const float* __restrict__ proj_b,
    const float* __restrict__ score_w,
    const ushort* __restrict__ wqf, const float* __restrict__ ff_b,
    float* __restrict__ out, int L)
{
    __shared__ ushort x_lds[M_][LSTR];   // conv x (A proj) -> o (A FF), bf16
    __shared__ float  x2f[M_][X2S];      // masked x (mix input), f32
    __shared__ float  xsred[8][M_];
    __shared__ float  wts[8][12][4];     // per-wave copy; tile = w>>1
    const int b  = blockIdx.x / BPB;
    const int l0 = (blockIdx.x % BPB) * M_;
    const int t  = threadIdx.x;
    const int w  = t >> 6, ln = t & 63;
    const int lr = ln & 15, q = ln >> 4;
    const int koff = q * 8;
    const int g   = t >> 7;              // row-group 0..3 (wave-uniform)
    const int ch0 = (t & 127) * 2;       // channel pair (conv & mix)
    const int base = g * 12;             // conv row base

    const int* seqp = seq + (size_t)b * L + l0;

    // ---- hoisted token loads; OOB (l>=L) -> -1 (true zero rows);
    //      PAD tokens stay 0 (emb[0] IS fed to conv, per reference) ----
    int tokv[15];
    #pragma unroll
    for (int r = 0; r < 15; ++r)
        tokv[r] = (l0 + base + r < L) ? seqp[base + r] : -1;

    // ---- validity mask: one coalesced lane-load + ballot ----
    unsigned long long vmask;
    {
        int sv = (ln < M_ && l0 + ln < L) ? seqp[ln] : 0;
        vmask = __ballot(sv > 0);
    }

    // slab registers: FULL set of 8 k8-slabs (64 VGPR)
    bf16x8 s00, s01, s10, s11, s20, s21, s30, s31;
    bf16x8 s40, s41, s50, s51, s60, s61, s70, s71;
    // issue ALL proj slabs now -> fully covered by conv (~2k cy)
    LDB2(s00, s01, wqp, 0);
    LDB2(s10, s11, wqp, 1);
    LDB2(s20, s21, wqp, 2);
    LDB2(s30, s31, wqp, 3);
    LDB2(s40, s41, wqp, 4);
    LDB2(s50, s51, wqp, 5);
    LDB2(s60, s61, wqp, 6);
    LDB2(s70, s71, wqp, 7);
    SBAR;

    // ---- conv: row-group g rows base..base+11, channel pair ch0;
    //      emb read f32, x16 (sqrt D) folded into taps; cvt_pk pack ----
    {
        float4 wa = *(const float4*)(conv_w + ch0 * 4);
        float4 wb = *(const float4*)(conv_w + ch0 * 4 + 4);
        wa.x *= 16.f; wa.y *= 16.f; wa.z *= 16.f; wa.w *= 16.f;
        wb.x *= 16.f; wb.y *= 16.f; wb.z *= 16.f; wb.w *= 16.f;
        const float cba = conv_b[ch0], cbb = conv_b[ch0 + 1];
        float2 er[15];
        #pragma unroll
        for (int r = 0; r < 15; ++r) {
            int sn_ = __builtin_amdgcn_readfirstlane(tokv[r]);
            float2 e_; e_.x = 0.f; e_.y = 0.f;
            if (sn_ >= 0) e_ = *(const float2*)(emb + (size_t)sn_ * D_ + ch0);
            er[r] = e_;
        }
        #pragma unroll
        for (int r = 0; r < 12; ++r) {
            float cx = fmaf(wa.x, er[r].x, fmaf(wa.y, er[r+1].x,
                       fmaf(wa.z, er[r+2].x, fmaf(wa.w, er[r+3].x, cba))));
            float cy = fmaf(wb.x, er[r].y, fmaf(wb.y, er[r+1].y,
                       fmaf(wb.z, er[r+2].y, fmaf(wb.w, er[r+3].y, cbb))));
            *(unsigned*)&x_lds[base + r][ch0] = cvtpk(cx, cy);
        }
    }
    __syncthreads();   // B0: conv done -> A readable

    // ---- proj GEMM: pure MFMA run, all slabs already in flight ----
    f32x4 acc[3][2];
    #pragma unroll
    for (int s = 0; s < 3; ++s)
        #pragma unroll
        for (int n = 0; n < 2; ++n) acc[s][n] = (f32x4){0.f, 0.f, 0.f, 0.f};
    MFMA6(acc, 0, s00, s01);
    MFMA6(acc, 1, s10, s11);
    MFMA6(acc, 2, s20, s21);
    MFMA6(acc, 3, s30, s31);
    MFMA6(acc, 4, s40, s41);
    MFMA6(acc, 5, s50, s51);
    MFMA6(acc, 6, s60, s61);
    MFMA6(acc, 7, s70, s71);

    // ---- epilogue: mask+bias -> x2f (f32, no pack) + score partials ----
    {
        float xsp[12];
        #pragma unroll
        for (int i = 0; i < 12; ++i) xsp[i] = 0.f;
        #pragma unroll
        for (int n = 0; n < 2; ++n) {
            int e = w * 32 + n * 16 + lr;
            float pb = proj_b[e], sw = score_w[e];
            #pragma unroll
            for (int s = 0; s < 3; ++s) {
                #pragma unroll
                for (int r = 0; r < 4; ++r) {
                    int row = s * 16 + q * 4 + r;
                    float v = ((vmask >> row) & 1ull) ? acc[s][n][r] + pb : 0.f;
                    x2f[row][e] = v;
                    xsp[s * 4 + r] = fmaf(v, sw, xsp[s * 4 + r]);
                }
            }
        }
        #pragma unroll
        for (int off = 1; off < 16; off <<= 1) {
            #pragma unroll
            for (int i = 0; i < 12; ++i) xsp[i] += __shfl_xor(xsp[i], off, 64);
        }
        if (lr == 0) {
            #pragma unroll
            for (int s = 0; s < 3; ++s)
                #pragma unroll
                for (int r = 0; r < 4; ++r)
                    xsred[w][s * 16 + q * 4 + r] = xsp[s * 4 + r];
        }
    }
    __syncthreads();   // B1: x2f + xsred complete; x_lds A-reads all done

    // issue 6 FF slabs NOW -> covered by wts+mix; last 2 after mix
    LDB2(s00, s01, wqf, 0);
    LDB2(s10, s11, wqf, 1);
    LDB2(s20, s21, wqf, 2);
    LDB2(s30, s31, wqf, 3);
    LDB2(s40, s41, wqf, 4);
    LDB2(s50, s51, wqf, 5);
    SBAR;

    // ---- softmax weights (per-wave redundant; lanes 0..11; tile = w>>1) ----
    if (ln < 12) {
        const int p = (w >> 1) * 12 + ln;   // global row
        // per-row total score (8-way cross-wave sum)
        float xt = xsred[0][p] + xsred[1][p] + xsred[2][p] + xsred[3][p]
                 + xsred[4][p] + xsred[5][p] + xsred[6][p] + xsred[7][p];
        // group-neighbor sums via shfl (BEFORE validity branch: sources active;
        // 12 | group bases so local index == in-tile index)
        int i2 = ln & ~1;
        float s2 = __shfl(xt, i2, 64) + __shfl(xt, i2 + 1, 64);
        int i3 = ln - (ln % 3);
        float s3 = __shfl(xt, i3, 64) + __shfl(xt, i3 + 1, 64)
                 + __shfl(xt, i3 + 2, 64);
        int i4 = ln & ~3;
        float s4 = __shfl(xt, i4, 64) + __shfl(xt, i4 + 1, 64)
                 + __shfl(xt, i4 + 2, 64) + __shfl(xt, i4 + 3, 64);
        if (!((vmask >> p) & 1ull)) {
            wts[w][ln][0] = wts[w][ln][1] = wts[w][ln][2] = wts[w][ln][3] = 0.f;
        } else {
            int r2 = p & ~1, r4 = p & ~3;
            int r3 = p - (p % 3);
            float c2 = (float)__popcll((vmask >> r2) & 3ull);    // >=1: p valid
            float c3 = (float)__popcll((vmask >> r3) & 7ull);
            float c4 = (float)__popcll((vmask >> r4) & 15ull);
            float m2 = s2 / c2, m3 = s3 / c3, m4 = s4 / c4;
            float mx = fmaxf(fmaxf(xt, m2), fmaxf(m3, m4));
            float q0 = __expf(xt - mx), q2 = __expf(m2 - mx);
            float q3 = __expf(m3 - mx), q4 = __expf(m4 - mx);
            float iZ = 1.f / (q0 + 2.f * q2 + 3.f * q3 + 4.f * q4);
            wts[w][ln][0] = q0 * iZ;
            wts[w][ln][1] = 2.f * q2 * iZ / c2;   // inv counts folded
            wts[w][ln][2] = 3.f * q3 * iZ / c3;
            wts[w][ln][3] = 4.f * q4 * iZ / c4;
        }
    }
    asm volatile("s_waitcnt lgkmcnt(0)" ::: "memory");
    SBAR;

    // ---- mix: tile g (= w>>1), channel pair ch0; f32 reads, cvt_pk out ----
    {
        const int r0 = g * 12;
        float2 xr[12];
        #pragma unroll
        for (int p = 0; p < 12; ++p)
            xr[p] = *(const float2*)&x2f[r0 + p][ch0];
        float s2x[6], s2y[6], s3x[4], s3y[4], s4x[3], s4y[3];
        #pragma unroll
        for (int j = 0; j < 6; ++j) {
            s2x[j] = xr[2*j].x + xr[2*j+1].x;
            s2y[j] = xr[2*j].y + xr[2*j+1].y;
        }
        #pragma unroll
        for (int j = 0; j < 4; ++j) {
            s3x[j] = xr[3*j].x + xr[3*j+1].x + xr[3*j+2].x;
            s3y[j] = xr[3*j].y + xr[3*j+1].y + xr[3*j+2].y;
        }
        #pragma unroll
        for (int j = 0; j < 3; ++j) {
            s4x[j] = xr[4*j].x + xr[4*j+1].x + xr[4*j+2].x + xr[4*j+3].x;
            s4y[j] = xr[4*j].y + xr[4*j+1].y + xr[4*j+2].y + xr[4*j+3].y;
        }
        #pragma unroll
        for (int p = 0; p < 12; ++p) {
            float4 wv = *(const float4*)&wts[w][p][0];
            float ox = wv.x*xr[p].x + wv.y*s2x[p>>1] + wv.z*s3x[p/3] + wv.w*s4x[p>>2];
            float oy = wv.x*xr[p].y + wv.y*s2y[p>>1] + wv.z*s3y[p/3] + wv.w*s4y[p>>2];
            *(unsigned*)&x_lds[r0 + p][ch0] = cvtpk(ox, oy);
        }
    }
    // last 2 FF slabs (regs s6*/s7* free since proj GEMM ended)
    LDB2(s60, s61, wqf, 6);
    LDB2(s70, s71, wqf, 7);
    SBAR;
    __syncthreads();   // B2: o rows done

    // ---- FF GEMM: pure MFMA run, all slabs in flight ----
    f32x4 ffa[3][2];
    #pragma unroll
    for (int s = 0; s < 3; ++s)
        #pragma unroll
        for (int n = 0; n < 2; ++n) ffa[s][n] = (f32x4){0.f, 0.f, 0.f, 0.f};
    MFMA6(ffa, 0, s00, s01);
    MFMA6(ffa, 1, s10, s11);
    MFMA6(ffa, 2, s20, s21);
    MFMA6(ffa, 3, s30, s31);
    MFMA6(ffa, 4, s40, s41);
    MFMA6(ffa, 5, s50, s51);
    MFMA6(ffa, 6, s60, s61);
    MFMA6(ffa, 7, s70, s71);

    // ---- store out = o + relu(ff + fb), l < L; NT: don't pollute L2 ----
    #pragma unroll
    for (int n = 0; n < 2; ++n) {
        int e = w * 32 + n * 16 + lr;
        float fb = ff_b[e];
        #pragma unroll
        for (int s = 0; s < 3; ++s) {
            #pragma unroll
            for (int r = 0; r < 4; ++r) {
                int row = s * 16 + q * 4 + r;
                int l = l0 + row;
                if (l < L) {
                    float o = bf2f(x_lds[row][e]);
                    __builtin_nontemporal_store(
                        o + fmaxf(ffa[s][n][r] + fb, 0.f),
                        &out[((size_t)b * L + l) * D_ + e]);
                }
            }
        }
    }
}

// ---------------------------------------------------------------------------
extern "C" void kernel_launch(void* const* d_in, const int* in_sizes, int n_in,
                              void* d_out, int out_size, void* d_ws, size_t ws_size,
                              hipStream_t stream) {
    const int*   seq     = (const int*)d_in[0];
    // d_in[1] = group_id : redundant (groups are pos//s, validity = seq!=0)
    const float* emb     = (const float*)d_in[2];
    const float* conv_w  = (const float*)d_in[3];
    const float* conv_b  = (const float*)d_in[4];
    const float* proj_w  = (const float*)d_in[5];
    const float* proj_b  = (const float*)d_in[6];
    const float* score_w = (const float*)d_in[7];
    // d_in[8] = score_b : constant shift, cancels in softmax
    const float* ff_w    = (const float*)d_in[9];
    const float* ff_b    = (const float*)d_in[10];
    float* out = (float*)d_out;

    const int L = 2048;
    const int B = in_sizes[0] / L;

    ushort* wqp = (ushort*)d_ws;          // [65536] bf16 fragment-major
    ushort* wqf = wqp + D_ * D_;          // [65536] bf16 fragment-major

    k_prep<<<D_ * D_ / 512, 256, 0, stream>>>(proj_w, ff_w, wqp, wqf);
    k_main<<<B * BPB, 512, 0, stream>>>(seq, emb, conv_w, conv_b, wqp, proj_b,
                                        score_w, wqf, ff_b, out, L);
}

// Round 8
// 28.736 us; speedup vs baseline: 1.0231x; 1.0231x over previous
//
#include <hip/hip_runtime.h>
#include <math.h>

// GBST forward. B=8, L=2048, D=256, NGRAM=4. R19 = R17 (best, 27.7us) +
// SINGLE-BUFFER merge to double occupancy:
//  - x2 buffer ELIMINATED. One buffer x_lds carries conv-x (proj A) ->
//    masked proj-out (epilogue writes it after a NEW barrier B0.5, since
//    conv-x is dead once the last MFMA6 A-read completes) -> mix rewrites
//    o IN PLACE (each thread reads only the 12x2 cells it overwrites;
//    reads land in regs before writes) -> FF A -> store o.
//  - LDS 53.8 -> 28.4 KB => 4 blocks/CU (32 waves/CU, HW max) vs R17's 2.
//    R14 counters: all pipes <15% busy, latency-bound => TLP is the lever.
//  - Cost: 4 barriers instead of 3.
// R18 post-mortem: full 8-slab prefetch + f32 x2 (78KB LDS) regressed ->
// reverted; R17's 4-deep ping-pong + bf16 x2 layout kept verbatim.
// Kept: NT out stores, hoisted tokens, vectorized k_prep, M=48/8-wave.

#define D_ 256
#define M_ 48                 // positions per block (3 stripes of 16; 12 | 48)
#define BPB 43                // ceil(2048/48)
#define LSTR 264              // ushort stride: 528B, 16B-aligned

typedef __attribute__((ext_vector_type(8))) short bf16x8;
typedef __attribute__((ext_vector_type(4))) float f32x4;

__device__ __forceinline__ ushort f2bf(float f) {
    union { float f; unsigned u; } v; v.f = f;
    unsigned r = v.u + 0x7fffu + ((v.u >> 16) & 1u);   // RNE
    return (ushort)(r >> 16);
}
__device__ __forceinline__ float bf2f(ushort h) {
    union { unsigned u; float f; } v; v.u = ((unsigned)h) << 16;
    return v.f;
}

// load one k8-slab (2 B-frags for this wave's n-pair), fragment-major
#define LDB2(v0, v1, W, K8) do { \
    const ushort* bp_ = (W) + ((size_t)((K8) * 16 + w * 2) * 64 + ln) * 8; \
    v0 = *(const bf16x8*)(bp_); \
    v1 = *(const bf16x8*)(bp_ + 512); \
} while (0)

// 6 MFMAs for one k8: 2 n-tiles x 3 m-stripes
#define MFMA6(ACC, K8, v0, v1) do { \
    bf16x8 a0_ = *(const bf16x8*)&x_lds[lr][(K8) * 32 + koff]; \
    bf16x8 a1_ = *(const bf16x8*)&x_lds[16 + lr][(K8) * 32 + koff]; \
    bf16x8 a2_ = *(const bf16x8*)&x_lds[32 + lr][(K8) * 32 + koff]; \
    ACC[0][0] = __builtin_amdgcn_mfma_f32_16x16x32_bf16(a0_, v0, ACC[0][0], 0, 0, 0); \
    ACC[1][0] = __builtin_amdgcn_mfma_f32_16x16x32_bf16(a1_, v0, ACC[1][0], 0, 0, 0); \
    ACC[2][0] = __builtin_amdgcn_mfma_f32_16x16x32_bf16(a2_, v0, ACC[2][0], 0, 0, 0); \
    ACC[0][1] = __builtin_amdgcn_mfma_f32_16x16x32_bf16(a0_, v1, ACC[0][1], 0, 0, 0); \
    ACC[1][1] = __builtin_amdgcn_mfma_f32_16x16x32_bf16(a1_, v1, ACC[1][1], 0, 0, 0); \
    ACC[2][1] = __builtin_amdgcn_mfma_f32_16x16x32_bf16(a2_, v1, ACC[2][1], 0, 0, 0); \
} while (0)

#define SBAR __builtin_amdgcn_sched_barrier(0)

// ---------------------------------------------------------------------------
// K0: proj_w/ff_w -> bf16 FRAGMENT-MAJOR, 2 elements/thread (j,j+1 pairs):
// wq[((k8*16+nb)*64+ln)*8+j] = w[(nb*16+(ln&15))*256 + k8*32+(ln>>4)*8+j]
// ---------------------------------------------------------------------------
__global__ __launch_bounds__(256) void k_prep(
    const float* __restrict__ pw, const float* __restrict__ fw,
    ushort* __restrict__ wqp, ushort* __restrict__ wqf)
{
    int i = (blockIdx.x * 256 + threadIdx.x) * 2;   // 0,2,..,65534
    int j  = i & 7;                                  // even
    int ln = (i >> 3) & 63;
    int nb = (i >> 9) & 15;
    int k8 = i >> 13;
    int er = nb * 16 + (ln & 15);
    int k  = k8 * 32 + (ln >> 4) * 8 + j;
    float2 p2 = *(const float2*)(pw + er * D_ + k);
    float2 f2 = *(const float2*)(fw + er * D_ + k);
    ushort2 po; po.x = f2bf(p2.x); po.y = f2bf(p2.y);
    ushort2 fo; fo.x = f2bf(f2.x); fo.y = f2bf(f2.y);
    *(ushort2*)(wqp + i) = po;
    *(ushort2*)(wqf + i) = fo;
}

// ---------------------------------------------------------------------------
// K1: 512 threads / 8 waves, M=48 positions, 4 barriers, single LDS buffer.
// ---------------------------------------------------------------------------
__global__ __launch_bounds__(512, 4) void k_main(
    const int* __restrict__ seq, const float* __restrict__ emb,
    const float* __restrict__ conv_w, const float* __restrict__ conv_b,
    const ushort* __restrict__ wqp, const float* __restrict__ proj_b,
    const float* __restrict__ score_w,
    const ushort* __restrict__ wqf, const float* __restrict__ ff_b,
    float* __restrict__ out, int L)
{
    __shared__ ushort x_lds[M_][LSTR];   // conv x -> masked x -> o (one buffer)
    __shared__ float xsred[8][M_];
    __shared__ float wts[8][12][4];      // per-wave copy; tile = w>>1
    const int b  = blockIdx.x / BPB;
    const int l0 = (blockIdx.x % BPB) * M_;
    const int t  = threadIdx.x;
    const int w  = t >> 6, ln = t & 63;
    const int lr = ln & 15, q = ln >> 4;
    const int koff = q * 8;
    const int g   = t >> 7;              // row-group 0..3 (wave-uniform)
    const int ch0 = (t & 127) * 2;       // channel pair (conv & mix)
    const int base = g * 12;             // conv row base

    const int* seqp = seq + (size_t)b * L + l0;

    // ---- hoisted token loads; OOB (l>=L) -> -1 (true zero rows);
    //      PAD tokens stay 0 (emb[0] IS fed to conv, per reference) ----
    int tokv[15];
    #pragma unroll
    for (int r = 0; r < 15; ++r)
        tokv[r] = (l0 + base + r < L) ? seqp[base + r] : -1;

    // ---- validity mask: one coalesced lane-load + ballot ----
    unsigned long long vmask;
    {
        int sv = (ln < M_ && l0 + ln < L) ? seqp[ln] : 0;
        vmask = __ballot(sv > 0);
    }

    // slab registers (4-deep ping-pong, shared by proj and FF pipelines)
    bf16x8 s00, s01, s10, s11, s20, s21, s30, s31;
    LDB2(s00, s01, wqp, 0);
    LDB2(s10, s11, wqp, 1);
    LDB2(s20, s21, wqp, 2);
    LDB2(s30, s31, wqp, 3);
    SBAR;

    // ---- conv: row-group g rows base..base+11, channel pair ch0;
    //      emb read f32, x16 (sqrt D) folded into taps ----
    {
        float4 wa = *(const float4*)(conv_w + ch0 * 4);
        float4 wb = *(const float4*)(conv_w + ch0 * 4 + 4);
        wa.x *= 16.f; wa.y *= 16.f; wa.z *= 16.f; wa.w *= 16.f;
        wb.x *= 16.f; wb.y *= 16.f; wb.z *= 16.f; wb.w *= 16.f;
        const float cba = conv_b[ch0], cbb = conv_b[ch0 + 1];
        float2 er[15];
        #pragma unroll
        for (int r = 0; r < 15; ++r) {
            int sn_ = __builtin_amdgcn_readfirstlane(tokv[r]);
            float2 e_; e_.x = 0.f; e_.y = 0.f;
            if (sn_ >= 0) e_ = *(const float2*)(emb + (size_t)sn_ * D_ + ch0);
            er[r] = e_;
        }
        #pragma unroll
        for (int r = 0; r < 12; ++r) {
            float cx = fmaf(wa.x, er[r].x, fmaf(wa.y, er[r+1].x,
                       fmaf(wa.z, er[r+2].x, fmaf(wa.w, er[r+3].x, cba))));
            float cy = fmaf(wb.x, er[r].y, fmaf(wb.y, er[r+1].y,
                       fmaf(wb.z, er[r+2].y, fmaf(wb.w, er[r+3].y, cbb))));
            *(unsigned*)&x_lds[base + r][ch0] =
                (unsigned)f2bf(cx) | ((unsigned)f2bf(cy) << 16);
        }
    }
    __syncthreads();   // B0: conv done -> A readable

    // ---- proj GEMM: 4-slab-deep pipeline, fully unrolled ----
    f32x4 acc[3][2];
    #pragma unroll
    for (int s = 0; s < 3; ++s)
        #pragma unroll
        for (int n = 0; n < 2; ++n) acc[s][n] = (f32x4){0.f, 0.f, 0.f, 0.f};
    MFMA6(acc, 0, s00, s01); LDB2(s00, s01, wqp, 4); SBAR;
    MFMA6(acc, 1, s10, s11); LDB2(s10, s11, wqp, 5); SBAR;
    MFMA6(acc, 2, s20, s21); LDB2(s20, s21, wqp, 6); SBAR;
    MFMA6(acc, 3, s30, s31); LDB2(s30, s31, wqp, 7); SBAR;
    MFMA6(acc, 4, s00, s01);
    MFMA6(acc, 5, s10, s11);
    MFMA6(acc, 6, s20, s21);
    MFMA6(acc, 7, s30, s31);
    __syncthreads();   // B0.5: all A-reads of conv-x done -> buffer reusable

    // ---- epilogue: mask+bias -> x_lds (in place) + score partials ----
    {
        float xsp[12];
        #pragma unroll
        for (int i = 0; i < 12; ++i) xsp[i] = 0.f;
        #pragma unroll
        for (int n = 0; n < 2; ++n) {
            int e = w * 32 + n * 16 + lr;
            float pb = proj_b[e], sw = score_w[e];
            #pragma unroll
            for (int s = 0; s < 3; ++s) {
                #pragma unroll
                for (int r = 0; r < 4; ++r) {
                    int row = s * 16 + q * 4 + r;
                    float v = ((vmask >> row) & 1ull) ? acc[s][n][r] + pb : 0.f;
                    x_lds[row][e] = f2bf(v);
                    xsp[s * 4 + r] = fmaf(v, sw, xsp[s * 4 + r]);
                }
            }
        }
        #pragma unroll
        for (int off = 1; off < 16; off <<= 1) {
            #pragma unroll
            for (int i = 0; i < 12; ++i) xsp[i] += __shfl_xor(xsp[i], off, 64);
        }
        if (lr == 0) {
            #pragma unroll
            for (int s = 0; s < 3; ++s)
                #pragma unroll
                for (int r = 0; r < 4; ++r)
                    xsred[w][s * 16 + q * 4 + r] = xsp[s * 4 + r];
        }
    }
    __syncthreads();   // B1: masked x + xsred complete

    // issue FF slabs 0..3 NOW -> latency hides under wts+mix VALU work
    LDB2(s00, s01, wqf, 0);
    LDB2(s10, s11, wqf, 1);
    LDB2(s20, s21, wqf, 2);
    LDB2(s30, s31, wqf, 3);
    SBAR;

    // ---- softmax weights (per-wave redundant; lanes 0..11; tile = w>>1) ----
    if (ln < 12) {
        const int p = (w >> 1) * 12 + ln;   // global row
        // per-row total score (8-way cross-wave sum)
        float xt = xsred[0][p] + xsred[1][p] + xsred[2][p] + xsred[3][p]
                 + xsred[4][p] + xsred[5][p] + xsred[6][p] + xsred[7][p];
        // group-neighbor sums via shfl (BEFORE validity branch: sources active;
        // 12 | group bases so local index == in-tile index)
        int i2 = ln & ~1;
        float s2 = __shfl(xt, i2, 64) + __shfl(xt, i2 + 1, 64);
        int i3 = ln - (ln % 3);
        float s3 = __shfl(xt, i3, 64) + __shfl(xt, i3 + 1, 64)
                 + __shfl(xt, i3 + 2, 64);
        int i4 = ln & ~3;
        float s4 = __shfl(xt, i4, 64) + __shfl(xt, i4 + 1, 64)
                 + __shfl(xt, i4 + 2, 64) + __shfl(xt, i4 + 3, 64);
        if (!((vmask >> p) & 1ull)) {
            wts[w][ln][0] = wts[w][ln][1] = wts[w][ln][2] = wts[w][ln][3] = 0.f;
        } else {
            int r2 = p & ~1, r4 = p & ~3;
            int r3 = p - (p % 3);
            float c2 = (float)__popcll((vmask >> r2) & 3ull);    // >=1: p valid
            float c3 = (float)__popcll((vmask >> r3) & 7ull);
            float c4 = (float)__popcll((vmask >> r4) & 15ull);
            float m2 = s2 / c2, m3 = s3 / c3, m4 = s4 / c4;
            float mx = fmaxf(fmaxf(xt, m2), fmaxf(m3, m4));
            float q0 = __expf(xt - mx), q2 = __expf(m2 - mx);
            float q3 = __expf(m3 - mx), q4 = __expf(m4 - mx);
            float iZ = 1.f / (q0 + 2.f * q2 + 3.f * q3 + 4.f * q4);
            wts[w][ln][0] = q0 * iZ;
            wts[w][ln][1] = 2.f * q2 * iZ / c2;   // inv counts folded
            wts[w][ln][2] = 3.f * q3 * iZ / c3;
            wts[w][ln][3] = 4.f * q4 * iZ / c4;
        }
    }
    asm volatile("s_waitcnt lgkmcnt(0)" ::: "memory");
    SBAR;

    // ---- mix: tile g (= w>>1), channel pair ch0; IN-PLACE o rewrite
    //      (each thread reads only the 12x2 cells it overwrites; reads
    //       complete into regs before writes) ----
    {
        const int r0 = g * 12;
        float2 xr[12];
        #pragma unroll
        for (int p = 0; p < 12; ++p) {
            unsigned v = *(const unsigned*)&x_lds[r0 + p][ch0];
            xr[p].x = bf2f((ushort)(v & 0xffff));
            xr[p].y = bf2f((ushort)(v >> 16));
        }
        float s2x[6], s2y[6], s3x[4], s3y[4], s4x[3], s4y[3];
        #pragma unroll
        for (int j = 0; j < 6; ++j) {
            s2x[j] = xr[2*j].x + xr[2*j+1].x;
            s2y[j] = xr[2*j].y + xr[2*j+1].y;
        }
        #pragma unroll
        for (int j = 0; j < 4; ++j) {
            s3x[j] = xr[3*j].x + xr[3*j+1].x + xr[3*j+2].x;
            s3y[j] = xr[3*j].y + xr[3*j+1].y + xr[3*j+2].y;
        }
        #pragma unroll
        for (int j = 0; j < 3; ++j) {
            s4x[j] = xr[4*j].x + xr[4*j+1].x + xr[4*j+2].x + xr[4*j+3].x;
            s4y[j] = xr[4*j].y + xr[4*j+1].y + xr[4*j+2].y + xr[4*j+3].y;
        }
        #pragma unroll
        for (int p = 0; p < 12; ++p) {
            float4 wv = *(const float4*)&wts[w][p][0];
            float ox = wv.x*xr[p].x + wv.y*s2x[p>>1] + wv.z*s3x[p/3] + wv.w*s4x[p>>2];
            float oy = wv.x*xr[p].y + wv.y*s2y[p>>1] + wv.z*s3y[p/3] + wv.w*s4y[p>>2];
            *(unsigned*)&x_lds[r0 + p][ch0] =
                (unsigned)f2bf(ox) | ((unsigned)f2bf(oy) << 16);
        }
    }
    __syncthreads();   // B2: o rows done

    // ---- FF GEMM: 4-slab-deep pipeline (slabs 0..3 already in flight) ----
    f32x4 ffa[3][2];
    #pragma unroll
    for (int s = 0; s < 3; ++s)
        #pragma unroll
        for (int n = 0; n < 2; ++n) ffa[s][n] = (f32x4){0.f, 0.f, 0.f, 0.f};
    MFMA6(ffa, 0, s00, s01); LDB2(s00, s01, wqf, 4); SBAR;
    MFMA6(ffa, 1, s10, s11); LDB2(s10, s11, wqf, 5); SBAR;
    MFMA6(ffa, 2, s20, s21); LDB2(s20, s21, wqf, 6); SBAR;
    MFMA6(ffa, 3, s30, s31); LDB2(s30, s31, wqf, 7); SBAR;
    MFMA6(ffa, 4, s00, s01);
    MFMA6(ffa, 5, s10, s11);
    MFMA6(ffa, 6, s20, s21);
    MFMA6(ffa, 7, s30, s31);

    // ---- store out = o + relu(ff + fb), l < L; NT: don't pollute L2 ----
    #pragma unroll
    for (int n = 0; n < 2; ++n) {
        int e = w * 32 + n * 16 + lr;
        float fb = ff_b[e];
        #pragma unroll
        for (int s = 0; s < 3; ++s) {
            #pragma unroll
            for (int r = 0; r < 4; ++r) {
                int row = s * 16 + q * 4 + r;
                int l = l0 + row;
                if (l < L) {
                    float o = bf2f(x_lds[row][e]);
                    __builtin_nontemporal_store(
                        o + fmaxf(ffa[s][n][r] + fb, 0.f),
                        &out[((size_t)b * L + l) * D_ + e]);
                }
            }
        }
    }
}

// ---------------------------------------------------------------------------
extern "C" void kernel_launch(void* const* d_in, const int* in_sizes, int n_in,
                              void* d_out, int out_size, void* d_ws, size_t ws_size,
                              hipStream_t stream) {
    const int*   seq     = (const int*)d_in[0];
    // d_in[1] = group_id : redundant (groups are pos//s, validity = seq!=0)
    const float* emb     = (const float*)d_in[2];
    const float* conv_w  = (const float*)d_in[3];
    const float* conv_b  = (const float*)d_in[4];
    const float* proj_w  = (const float*)d_in[5];
    const float* proj_b  = (const float*)d_in[6];
    const float* score_w = (const float*)d_in[7];
    // d_in[8] = score_b : constant shift, cancels in softmax
    const float* ff_w    = (const float*)d_in[9];
    const float* ff_b    = (const float*)d_in[10];
    float* out = (float*)d_out;

    const int L = 2048;
    const int B = in_sizes[0] / L;

    ushort* wqp = (ushort*)d_ws;          // [65536] bf16 fragment-major
    ushort* wqf = wqp + D_ * D_;          // [65536] bf16 fragment-major

    k_prep<<<D_ * D_ / 512, 256, 0, stream>>>(proj_w, ff_w, wqp, wqf);
    k_main<<<B * BPB, 512, 0, stream>>>(seq, emb, conv_w, conv_b, wqp, proj_b,
                                        score_w, wqf, ff_b, out, L);
}

// Round 9
// 27.076 us; speedup vs baseline: 1.0858x; 1.0613x over previous
//
#include <hip/hip_runtime.h>
#include <math.h>

// GBST forward. B=8, L=2048, D=256, NGRAM=4. R20 = R17 (best, 27.7us) +
// v_cvt_pk_bf16_f32 ONLY (single-variable experiment).
// Model after R19: dur = prep+gap (~4us) + k_main (~23us); k_main wall time
// at short-dispatch low clock = VALU issue count (~800/thr * 8 waves/SIMD
// ~ 10us @ ~650MHz) + fixed latency chain. MFMA count (R13), L2 traffic
// (R13), code size (R15), prefetch depth (R18), TLP (R19) all falsified ->
// the untested term is VALU count. cvtpk cuts ~240 VALU/thr (~30%):
// conv pack 12x~8->12x1, mix pack 12x~8->12x1, epilogue x2 pack 24x~4->24x1.
// R18 already validated cvtpk numerics (same absmax); it bundled two
// regressing changes -- here nothing else moves vs R17.

#define D_ 256
#define M_ 48                 // positions per block (3 stripes of 16; 12 | 48)
#define BPB 43                // ceil(2048/48)
#define LSTR 264              // ushort stride: 528B, 16B-aligned

typedef __attribute__((ext_vector_type(8))) short bf16x8;
typedef __attribute__((ext_vector_type(4))) float f32x4;

__device__ __forceinline__ float bf2f(ushort h) {
    union { unsigned u; float f; } v; v.u = ((unsigned)h) << 16;
    return v.f;
}
// packed RNE f32x2 -> bf16x2 (lo = first arg); 1 VALU op
__device__ __forceinline__ unsigned cvtpk(float lo, float hi) {
    unsigned r;
    asm("v_cvt_pk_bf16_f32 %0, %1, %2" : "=v"(r) : "v"(lo), "v"(hi));
    return r;
}

// load one k8-slab (2 B-frags for this wave's n-pair), fragment-major
#define LDB2(v0, v1, W, K8) do { \
    const ushort* bp_ = (W) + ((size_t)((K8) * 16 + w * 2) * 64 + ln) * 8; \
    v0 = *(const bf16x8*)(bp_); \
    v1 = *(const bf16x8*)(bp_ + 512); \
} while (0)

// 6 MFMAs for one k8: 2 n-tiles x 3 m-stripes
#define MFMA6(ACC, K8, v0, v1) do { \
    bf16x8 a0_ = *(const bf16x8*)&x_lds[lr][(K8) * 32 + koff]; \
    bf16x8 a1_ = *(const bf16x8*)&x_lds[16 + lr][(K8) * 32 + koff]; \
    bf16x8 a2_ = *(const bf16x8*)&x_lds[32 + lr][(K8) * 32 + koff]; \
    ACC[0][0] = __builtin_amdgcn_mfma_f32_16x16x32_bf16(a0_, v0, ACC[0][0], 0, 0, 0); \
    ACC[1][0] = __builtin_amdgcn_mfma_f32_16x16x32_bf16(a1_, v0, ACC[1][0], 0, 0, 0); \
    ACC[2][0] = __builtin_amdgcn_mfma_f32_16x16x32_bf16(a2_, v0, ACC[2][0], 0, 0, 0); \
    ACC[0][1] = __builtin_amdgcn_mfma_f32_16x16x32_bf16(a0_, v1, ACC[0][1], 0, 0, 0); \
    ACC[1][1] = __builtin_amdgcn_mfma_f32_16x16x32_bf16(a1_, v1, ACC[1][1], 0, 0, 0); \
    ACC[2][1] = __builtin_amdgcn_mfma_f32_16x16x32_bf16(a2_, v1, ACC[2][1], 0, 0, 0); \
} while (0)

#define SBAR __builtin_amdgcn_sched_barrier(0)

// ---------------------------------------------------------------------------
// K0: proj_w/ff_w -> bf16 FRAGMENT-MAJOR, 2 elements/thread (j,j+1 pairs):
// wq[((k8*16+nb)*64+ln)*8+j] = w[(nb*16+(ln&15))*256 + k8*32+(ln>>4)*8+j]
// ---------------------------------------------------------------------------
__global__ __launch_bounds__(256) void k_prep(
    const float* __restrict__ pw, const float* __restrict__ fw,
    ushort* __restrict__ wqp, ushort* __restrict__ wqf)
{
    int i = (blockIdx.x * 256 + threadIdx.x) * 2;   // 0,2,..,65534
    int j  = i & 7;                                  // even
    int ln = (i >> 3) & 63;
    int nb = (i >> 9) & 15;
    int k8 = i >> 13;
    int er = nb * 16 + (ln & 15);
    int k  = k8 * 32 + (ln >> 4) * 8 + j;
    float2 p2 = *(const float2*)(pw + er * D_ + k);
    float2 f2 = *(const float2*)(fw + er * D_ + k);
    *(unsigned*)(wqp + i) = cvtpk(p2.x, p2.y);
    *(unsigned*)(wqf + i) = cvtpk(f2.x, f2.y);
}

// ---------------------------------------------------------------------------
// K1: 512 threads / 8 waves, M=48 positions, 3 barriers, 4-deep GEMM pipes.
// ---------------------------------------------------------------------------
__global__ __launch_bounds__(512, 4) void k_main(
    const int* __restrict__ seq, const float* __restrict__ emb,
    const float* __restrict__ conv_w, const float* __restrict__ conv_b,
    const ushort* __restrict__ wqp, const float* __restrict__ proj_b,
    const float* __restrict__ score_w,
    const ushort* __restrict__ wqf, const float* __restrict__ ff_b,
    float* __restrict__ out, int L)
{
    __shared__ ushort x_lds[M_][LSTR];   // conv x (A proj) -> o (A FF)
    __shared__ ushort x2[M_][LSTR];      // masked x (mix input)
    __shared__ float xsred[8][M_];
    __shared__ float wts[8][12][4];      // per-wave copy; tile = w>>1
    const int b  = blockIdx.x / BPB;
    const int l0 = (blockIdx.x % BPB) * M_;
    const int t  = threadIdx.x;
    const int w  = t >> 6, ln = t & 63;
    const int lr = ln & 15, q = ln >> 4;
    const int koff = q * 8;
    const int g   = t >> 7;              // row-group 0..3 (wave-uniform)
    const int ch0 = (t & 127) * 2;       // channel pair (conv & mix)
    const int base = g * 12;             // conv row base

    const int* seqp = seq + (size_t)b * L + l0;

    // ---- hoisted token loads; OOB (l>=L) -> -1 (true zero rows);
    //      PAD tokens stay 0 (emb[0] IS fed to conv, per reference) ----
    int tokv[15];
    #pragma unroll
    for (int r = 0; r < 15; ++r)
        tokv[r] = (l0 + base + r < L) ? seqp[base + r] : -1;

    // ---- validity mask: one coalesced lane-load + ballot ----
    unsigned long long vmask;
    {
        int sv = (ln < M_ && l0 + ln < L) ? seqp[ln] : 0;
        vmask = __ballot(sv > 0);
    }

    // slab registers (4-deep ping-pong, shared by proj and FF pipelines)
    bf16x8 s00, s01, s10, s11, s20, s21, s30, s31;
    LDB2(s00, s01, wqp, 0);
    LDB2(s10, s11, wqp, 1);
    LDB2(s20, s21, wqp, 2);
    LDB2(s30, s31, wqp, 3);
    SBAR;

    // ---- conv: row-group g rows base..base+11, channel pair ch0;
    //      emb read f32, x16 (sqrt D) folded into taps; cvtpk pack ----
    {
        float4 wa = *(const float4*)(conv_w + ch0 * 4);
        float4 wb = *(const float4*)(conv_w + ch0 * 4 + 4);
        wa.x *= 16.f; wa.y *= 16.f; wa.z *= 16.f; wa.w *= 16.f;
        wb.x *= 16.f; wb.y *= 16.f; wb.z *= 16.f; wb.w *= 16.f;
        const float cba = conv_b[ch0], cbb = conv_b[ch0 + 1];
        float2 er[15];
        #pragma unroll
        for (int r = 0; r < 15; ++r) {
            int sn_ = __builtin_amdgcn_readfirstlane(tokv[r]);
            float2 e_; e_.x = 0.f; e_.y = 0.f;
            if (sn_ >= 0) e_ = *(const float2*)(emb + (size_t)sn_ * D_ + ch0);
            er[r] = e_;
        }
        #pragma unroll
        for (int r = 0; r < 12; ++r) {
            float cx = fmaf(wa.x, er[r].x, fmaf(wa.y, er[r+1].x,
                       fmaf(wa.z, er[r+2].x, fmaf(wa.w, er[r+3].x, cba))));
            float cy = fmaf(wb.x, er[r].y, fmaf(wb.y, er[r+1].y,
                       fmaf(wb.z, er[r+2].y, fmaf(wb.w, er[r+3].y, cbb))));
            *(unsigned*)&x_lds[base + r][ch0] = cvtpk(cx, cy);
        }
    }
    __syncthreads();   // B0: conv done -> A readable

    // ---- proj GEMM: 4-slab-deep pipeline, fully unrolled ----
    f32x4 acc[3][2];
    #pragma unroll
    for (int s = 0; s < 3; ++s)
        #pragma unroll
        for (int n = 0; n < 2; ++n) acc[s][n] = (f32x4){0.f, 0.f, 0.f, 0.f};
    MFMA6(acc, 0, s00, s01); LDB2(s00, s01, wqp, 4); SBAR;
    MFMA6(acc, 1, s10, s11); LDB2(s10, s11, wqp, 5); SBAR;
    MFMA6(acc, 2, s20, s21); LDB2(s20, s21, wqp, 6); SBAR;
    MFMA6(acc, 3, s30, s31); LDB2(s30, s31, wqp, 7); SBAR;
    MFMA6(acc, 4, s00, s01);
    MFMA6(acc, 5, s10, s11);
    MFMA6(acc, 6, s20, s21);
    MFMA6(acc, 7, s30, s31);

    // ---- epilogue: mask+bias -> x2 (cvtpk single) + score partials ----
    {
        float xsp[12];
        #pragma unroll
        for (int i = 0; i < 12; ++i) xsp[i] = 0.f;
        #pragma unroll
        for (int n = 0; n < 2; ++n) {
            int e = w * 32 + n * 16 + lr;
            float pb = proj_b[e], sw = score_w[e];
            #pragma unroll
            for (int s = 0; s < 3; ++s) {
                #pragma unroll
                for (int r = 0; r < 4; ++r) {
                    int row = s * 16 + q * 4 + r;
                    float v = ((vmask >> row) & 1ull) ? acc[s][n][r] + pb : 0.f;
                    x2[row][e] = (ushort)cvtpk(v, v);   // RNE, 1 VALU
                    xsp[s * 4 + r] = fmaf(v, sw, xsp[s * 4 + r]);
                }
            }
        }
        #pragma unroll
        for (int off = 1; off < 16; off <<= 1) {
            #pragma unroll
            for (int i = 0; i < 12; ++i) xsp[i] += __shfl_xor(xsp[i], off, 64);
        }
        if (lr == 0) {
            #pragma unroll
            for (int s = 0; s < 3; ++s)
                #pragma unroll
                for (int r = 0; r < 4; ++r)
                    xsred[w][s * 16 + q * 4 + r] = xsp[s * 4 + r];
        }
    }
    __syncthreads();   // B1: x2 + xsred complete; x_lds A-reads all done

    // issue FF slabs 0..3 NOW -> latency hides under wts+mix VALU work
    LDB2(s00, s01, wqf, 0);
    LDB2(s10, s11, wqf, 1);
    LDB2(s20, s21, wqf, 2);
    LDB2(s30, s31, wqf, 3);
    SBAR;

    // ---- softmax weights (per-wave redundant; lanes 0..11; tile = w>>1) ----
    if (ln < 12) {
        const int p = (w >> 1) * 12 + ln;   // global row
        // per-row total score (8-way cross-wave sum)
        float xt = xsred[0][p] + xsred[1][p] + xsred[2][p] + xsred[3][p]
                 + xsred[4][p] + xsred[5][p] + xsred[6][p] + xsred[7][p];
        // group-neighbor sums via shfl (BEFORE validity branch: sources active;
        // 12 | group bases so local index == in-tile index)
        int i2 = ln & ~1;
        float s2 = __shfl(xt, i2, 64) + __shfl(xt, i2 + 1, 64);
        int i3 = ln - (ln % 3);
        float s3 = __shfl(xt, i3, 64) + __shfl(xt, i3 + 1, 64)
                 + __shfl(xt, i3 + 2, 64);
        int i4 = ln & ~3;
        float s4 = __shfl(xt, i4, 64) + __shfl(xt, i4 + 1, 64)
                 + __shfl(xt, i4 + 2, 64) + __shfl(xt, i4 + 3, 64);
        if (!((vmask >> p) & 1ull)) {
            wts[w][ln][0] = wts[w][ln][1] = wts[w][ln][2] = wts[w][ln][3] = 0.f;
        } else {
            int r2 = p & ~1, r4 = p & ~3;
            int r3 = p - (p % 3);
            float c2 = (float)__popcll((vmask >> r2) & 3ull);    // >=1: p valid
            float c3 = (float)__popcll((vmask >> r3) & 7ull);
            float c4 = (float)__popcll((vmask >> r4) & 15ull);
            float m2 = s2 / c2, m3 = s3 / c3, m4 = s4 / c4;
            float mx = fmaxf(fmaxf(xt, m2), fmaxf(m3, m4));
            float q0 = __expf(xt - mx), q2 = __expf(m2 - mx);
            float q3 = __expf(m3 - mx), q4 = __expf(m4 - mx);
            float iZ = 1.f / (q0 + 2.f * q2 + 3.f * q3 + 4.f * q4);
            wts[w][ln][0] = q0 * iZ;
            wts[w][ln][1] = 2.f * q2 * iZ / c2;   // inv counts folded
            wts[w][ln][2] = 3.f * q3 * iZ / c3;
            wts[w][ln][3] = 4.f * q4 * iZ / c4;
        }
    }
    asm volatile("s_waitcnt lgkmcnt(0)" ::: "memory");
    SBAR;

    // ---- mix: tile g (= w>>1), channel pair ch0; cvtpk pack out ----
    {
        const int r0 = g * 12;
        float2 xr[12];
        #pragma unroll
        for (int p = 0; p < 12; ++p) {
            unsigned v = *(const unsigned*)&x2[r0 + p][ch0];
            xr[p].x = bf2f((ushort)(v & 0xffff));
            xr[p].y = bf2f((ushort)(v >> 16));
        }
        float s2x[6], s2y[6], s3x[4], s3y[4], s4x[3], s4y[3];
        #pragma unroll
        for (int j = 0; j < 6; ++j) {
            s2x[j] = xr[2*j].x + xr[2*j+1].x;
            s2y[j] = xr[2*j].y + xr[2*j+1].y;
        }
        #pragma unroll
        for (int j = 0; j < 4; ++j) {
            s3x[j] = xr[3*j].x + xr[3*j+1].x + xr[3*j+2].x;
            s3y[j] = xr[3*j].y + xr[3*j+1].y + xr[3*j+2].y;
        }
        #pragma unroll
        for (int j = 0; j < 3; ++j) {
            s4x[j] = xr[4*j].x + xr[4*j+1].x + xr[4*j+2].x + xr[4*j+3].x;
            s4y[j] = xr[4*j].y + xr[4*j+1].y + xr[4*j+2].y + xr[4*j+3].y;
        }
        #pragma unroll
        for (int p = 0; p < 12; ++p) {
            float4 wv = *(const float4*)&wts[w][p][0];
            float ox = wv.x*xr[p].x + wv.y*s2x[p>>1] + wv.z*s3x[p/3] + wv.w*s4x[p>>2];
            float oy = wv.x*xr[p].y + wv.y*s2y[p>>1] + wv.z*s3y[p/3] + wv.w*s4y[p>>2];
            *(unsigned*)&x_lds[r0 + p][ch0] = cvtpk(ox, oy);
        }
    }
    __syncthreads();   // B2: o rows done

    // ---- FF GEMM: 4-slab-deep pipeline (slabs 0..3 already in flight) ----
    f32x4 ffa[3][2];
    #pragma unroll
    for (int s = 0; s < 3; ++s)
        #pragma unroll
        for (int n = 0; n < 2; ++n) ffa[s][n] = (f32x4){0.f, 0.f, 0.f, 0.f};
    MFMA6(ffa, 0, s00, s01); LDB2(s00, s01, wqf, 4); SBAR;
    MFMA6(ffa, 1, s10, s11); LDB2(s10, s11, wqf, 5); SBAR;
    MFMA6(ffa, 2, s20, s21); LDB2(s20, s21, wqf, 6); SBAR;
    MFMA6(ffa, 3, s30, s31); LDB2(s30, s31, wqf, 7); SBAR;
    MFMA6(ffa, 4, s00, s01);
    MFMA6(ffa, 5, s10, s11);
    MFMA6(ffa, 6, s20, s21);
    MFMA6(ffa, 7, s30, s31);

    // ---- store out = o + relu(ff + fb), l < L; NT: don't pollute L2 ----
    #pragma unroll
    for (int n = 0; n < 2; ++n) {
        int e = w * 32 + n * 16 + lr;
        float fb = ff_b[e];
        #pragma unroll
        for (int s = 0; s < 3; ++s) {
            #pragma unroll
            for (int r = 0; r < 4; ++r) {
                int row = s * 16 + q * 4 + r;
                int l = l0 + row;
                if (l < L) {
                    float o = bf2f(x_lds[row][e]);
                    __builtin_nontemporal_store(
                        o + fmaxf(ffa[s][n][r] + fb, 0.f),
                        &out[((size_t)b * L + l) * D_ + e]);
                }
            }
        }
    }
}

// ---------------------------------------------------------------------------
extern "C" void kernel_launch(void* const* d_in, const int* in_sizes, int n_in,
                              void* d_out, int out_size, void* d_ws, size_t ws_size,
                              hipStream_t stream) {
    const int*   seq     = (const int*)d_in[0];
    // d_in[1] = group_id : redundant (groups are pos//s, validity = seq!=0)
    const float* emb     = (const float*)d_in[2];
    const float* conv_w  = (const float*)d_in[3];
    const float* conv_b  = (const float*)d_in[4];
    const float* proj_w  = (const float*)d_in[5];
    const float* proj_b  = (const float*)d_in[6];
    const float* score_w = (const float*)d_in[7];
    // d_in[8] = score_b : constant shift, cancels in softmax
    const float* ff_w    = (const float*)d_in[9];
    const float* ff_b    = (const float*)d_in[10];
    float* out = (float*)d_out;

    const int L = 2048;
    const int B = in_sizes[0] / L;

    ushort* wqp = (ushort*)d_ws;          // [65536] bf16 fragment-major
    ushort* wqf = wqp + D_ * D_;          // [65536] bf16 fragment-major

    k_prep<<<D_ * D_ / 512, 256, 0, stream>>>(proj_w, ff_w, wqp, wqf);
    k_main<<<B * BPB, 512, 0, stream>>>(seq, emb, conv_w, conv_b, wqp, proj_b,
                                        score_w, wqf, ff_b, out, L);
}